// Round 1
// baseline (1279.027 us; speedup 1.0000x reference)
//
#include <hip/hip_runtime.h>

#define Bsz 4
#define Cch 64
#define Hh 128
#define Ww 128
#define NOFF 18     // 2*3*3 offset channels
#define CK 576      // 64*9 reduction length for deform einsum
#define SMP_STRIDE 580

// ---------------------------------------------------------------------------
// Kernel A0: transpose offset weight [oc][ci][tap] -> [ci][tap][oc]
// so the conv inner loop reads 18 contiguous floats at a wave-uniform address.
__global__ __launch_bounds__(256) void transpose_woff(const float* __restrict__ wo,
                                                      float* __restrict__ wt) {
    int t = blockIdx.x * 256 + threadIdx.x;
    if (t >= NOFF * 128 * 9) return;
    int oc = t % NOFF;
    int rest = t / NOFF;
    int tap = rest % 9;
    int ci = rest / 9;
    wt[t] = wo[(oc * 128 + ci) * 9 + tap];
}

// ---------------------------------------------------------------------------
// Kernel A: offset conv (in=concat(x,ref) 128ch, out=18ch, 3x3 pad1) + clip.
// One thread per output pixel, all 18 channels in registers.
// Output layout: offs[b][h][w][18]
__global__ __launch_bounds__(256) void offset_conv(const float* __restrict__ x,
                                                   const float* __restrict__ ref,
                                                   const float* __restrict__ wt,
                                                   const float* __restrict__ bias,
                                                   float* __restrict__ offs) {
    int b = blockIdx.x >> 6;
    int hp = blockIdx.x & 63;
    int tid = threadIdx.x;
    int h = hp * 2 + (tid >> 7);
    int w = tid & 127;

    float acc[NOFF];
#pragma unroll
    for (int oc = 0; oc < NOFF; ++oc) acc[oc] = bias[oc];

    for (int ci = 0; ci < 128; ++ci) {
        const float* src = (ci < Cch)
            ? (x + (size_t)(b * Cch + ci) * (Hh * Ww))
            : (ref + (size_t)(b * Cch + ci - Cch) * (Hh * Ww));
#pragma unroll
        for (int dy = 0; dy < 3; ++dy) {
            int yy = h + dy - 1;
            if ((unsigned)yy >= (unsigned)Hh) continue;
            const float* row = src + yy * Ww;
#pragma unroll
            for (int dx = 0; dx < 3; ++dx) {
                int xx = w + dx - 1;
                float v = ((unsigned)xx < (unsigned)Ww) ? row[xx] : 0.0f;
                const float* wp = wt + (ci * 9 + dy * 3 + dx) * NOFF;  // uniform addr -> s_load
#pragma unroll
                for (int oc = 0; oc < NOFF; ++oc)
                    acc[oc] = fmaf(v, wp[oc], acc[oc]);
            }
        }
    }

    float* op = offs + (size_t)((b * Hh + h) * Ww + w) * NOFF;
#pragma unroll
    for (int oc = 0; oc < NOFF; ++oc) {
        float v = acc[oc];
        v = fminf(fmaxf(v, -10.0f), 10.0f);
        op[oc] = v;
    }
}

// ---------------------------------------------------------------------------
// Kernel B: deformable conv. One block per (b, h, 16-wide pixel strip).
// Phase 1a: 144 coord sets (pixel x tap) into LDS.
// Phase 1b: 9216 bilinear samples (pixel x tap x channel) into LDS smp.
// Phase 2:  out[p][o] = sum_ck smp[p][ck] * W[o][ck]; wave wv owns o in
//           [wv*16, wv*16+16); lane = p*4+osub handles o = wv*16+osub+4j.
__global__ __launch_bounds__(256) void deform(const float* __restrict__ x,
                                              const float* __restrict__ wflat,
                                              const float* __restrict__ offs,
                                              float* __restrict__ out) {
    __shared__ float coords[144][4];            // fy0, fx0, ty, tx
    __shared__ float smp[16][SMP_STRIDE];       // [pixel][c*9+k], padded stride

    int bi = blockIdx.x;
    int b = bi >> 10;            // H*(W/16) = 128*8 = 1024 blocks per batch
    int rem = bi & 1023;
    int h = rem >> 3;
    int w0 = (rem & 7) << 4;
    int tid = threadIdx.x;

    if (tid < 144) {
        int p = tid / 9, k = tid % 9;
        int ky = k / 3, kx = k % 3;
        const float* op = offs + (size_t)((b * Hh + h) * Ww + w0 + p) * NOFF;
        float dy = op[k * 2 + 0];
        float dx = op[k * 2 + 1];
        float ys = (float)(h - 1 + ky) + dy;
        float xs = (float)(w0 + p - 1 + kx) + dx;
        float fy = floorf(ys), fx = floorf(xs);
        coords[tid][0] = fy;
        coords[tid][1] = fx;
        coords[tid][2] = ys - fy;
        coords[tid][3] = xs - fx;
    }
    __syncthreads();

    for (int it = 0; it < 36; ++it) {
        int t = it * 256 + tid;          // t = c*144 + k*16 + p
        int p = t & 15;
        int k = (t >> 4) % 9;
        int c = t / 144;
        const float4 cd = *(const float4*)coords[p * 9 + k];
        int iy0 = (int)cd.x;
        int ix0 = (int)cd.y;
        float ty = cd.z, tx = cd.w;
        const float* xp = x + (size_t)(b * Cch + c) * (Hh * Ww);
        float v00 = 0.f, v01 = 0.f, v10 = 0.f, v11 = 0.f;
        bool x0v = (unsigned)ix0 < (unsigned)Ww;
        bool x1v = (unsigned)(ix0 + 1) < (unsigned)Ww;
        if ((unsigned)iy0 < (unsigned)Hh) {
            const float* r = xp + iy0 * Ww;
            if (x0v) v00 = r[ix0];
            if (x1v) v01 = r[ix0 + 1];
        }
        if ((unsigned)(iy0 + 1) < (unsigned)Hh) {
            const float* r = xp + (iy0 + 1) * Ww;
            if (x0v) v10 = r[ix0];
            if (x1v) v11 = r[ix0 + 1];
        }
        float s = (v00 * (1.f - tx) + v01 * tx) * (1.f - ty)
                + (v10 * (1.f - tx) + v11 * tx) * ty;
        smp[p][c * 9 + k] = s;
    }
    __syncthreads();

    int wv = tid >> 6;
    int lane = tid & 63;
    int p = lane >> 2;
    int osub = lane & 3;
    int obase = wv * 16 + osub;      // o = obase + 4*j, j=0..3

    float acc0 = 0.f, acc1 = 0.f, acc2 = 0.f, acc3 = 0.f;
    const float* wp0 = wflat + (size_t)(obase + 0) * CK;
    const float* wp1 = wflat + (size_t)(obase + 4) * CK;
    const float* wp2 = wflat + (size_t)(obase + 8) * CK;
    const float* wp3 = wflat + (size_t)(obase + 12) * CK;
    const float* sp = smp[p];

    for (int ck = 0; ck < CK; ck += 4) {
        float4 s4 = *(const float4*)(sp + ck);
        float4 a0 = *(const float4*)(wp0 + ck);
        float4 a1 = *(const float4*)(wp1 + ck);
        float4 a2 = *(const float4*)(wp2 + ck);
        float4 a3 = *(const float4*)(wp3 + ck);
        acc0 = fmaf(s4.x, a0.x, acc0); acc0 = fmaf(s4.y, a0.y, acc0);
        acc0 = fmaf(s4.z, a0.z, acc0); acc0 = fmaf(s4.w, a0.w, acc0);
        acc1 = fmaf(s4.x, a1.x, acc1); acc1 = fmaf(s4.y, a1.y, acc1);
        acc1 = fmaf(s4.z, a1.z, acc1); acc1 = fmaf(s4.w, a1.w, acc1);
        acc2 = fmaf(s4.x, a2.x, acc2); acc2 = fmaf(s4.y, a2.y, acc2);
        acc2 = fmaf(s4.z, a2.z, acc2); acc2 = fmaf(s4.w, a2.w, acc2);
        acc3 = fmaf(s4.x, a3.x, acc3); acc3 = fmaf(s4.y, a3.y, acc3);
        acc3 = fmaf(s4.z, a3.z, acc3); acc3 = fmaf(s4.w, a3.w, acc3);
    }

    size_t ob = (size_t)b * Cch * (Hh * Ww) + (size_t)h * Ww + w0 + p;
    out[ob + (size_t)(obase + 0) * (Hh * Ww)] = acc0;
    out[ob + (size_t)(obase + 4) * (Hh * Ww)] = acc1;
    out[ob + (size_t)(obase + 8) * (Hh * Ww)] = acc2;
    out[ob + (size_t)(obase + 12) * (Hh * Ww)] = acc3;
}

// ---------------------------------------------------------------------------
extern "C" void kernel_launch(void* const* d_in, const int* in_sizes, int n_in,
                              void* d_out, int out_size, void* d_ws, size_t ws_size,
                              hipStream_t stream) {
    const float* x      = (const float*)d_in[0];
    const float* ref    = (const float*)d_in[1];
    const float* wo     = (const float*)d_in[2];
    const float* bias   = (const float*)d_in[3];
    const float* weight = (const float*)d_in[4];
    float* out = (float*)d_out;

    float* wt   = (float*)d_ws;                       // 20736 floats (83 KB)
    float* offs = (float*)((char*)d_ws + 131072);     // 4*128*128*18 floats (4.5 MB)

    hipLaunchKernelGGL(transpose_woff, dim3(81), dim3(256), 0, stream, wo, wt);
    hipLaunchKernelGGL(offset_conv, dim3(Bsz * 64), dim3(256), 0, stream,
                       x, ref, wt, bias, offs);
    hipLaunchKernelGGL(deform, dim3(Bsz * Hh * (Ww / 16)), dim3(256), 0, stream,
                       x, weight, offs, out);
}

// Round 2
// 331.825 us; speedup vs baseline: 3.8545x; 3.8545x over previous
//
#include <hip/hip_runtime.h>

#define Bsz 4
#define Cch 64
#define Hh 128
#define Ww 128
#define NOFF 18     // 2*3*3 offset channels
#define CK 576      // 64*9 reduction length for deform einsum
#define CKPAD 584   // smp row stride in bf16 elems: 584*2B=1168B -> 2-way bank alias only

typedef __attribute__((ext_vector_type(8))) short short8;
typedef __attribute__((ext_vector_type(4))) float floatx4;

__device__ __forceinline__ unsigned short f2bf(float f) {
    union { float f; unsigned u; } v; v.f = f;
    unsigned r = v.u + 0x7fff + ((v.u >> 16) & 1);   // round-to-nearest-even
    return (unsigned short)(r >> 16);
}

// ---------------------------------------------------------------------------
// Kernel A0: transpose offset weight [oc][ci][tap] -> [ci][tap][oc]
__global__ __launch_bounds__(256) void transpose_woff(const float* __restrict__ wo,
                                                      float* __restrict__ wt) {
    int t = blockIdx.x * 256 + threadIdx.x;
    if (t >= NOFF * 128 * 9) return;
    int oc = t % NOFF;
    int rest = t / NOFF;
    int tap = rest % 9;
    int ci = rest / 9;
    wt[t] = wo[(oc * 128 + ci) * 9 + tap];
}

// Kernel A1: convert deform weight [64][576] f32 -> bf16
__global__ __launch_bounds__(256) void convert_w(const float* __restrict__ w,
                                                 unsigned short* __restrict__ wbf) {
    int t = blockIdx.x * 256 + threadIdx.x;
    if (t < Cch * CK) wbf[t] = f2bf(w[t]);
}

// ---------------------------------------------------------------------------
// Kernel A: offset conv (in=concat(x,ref) 128ch, out=18ch, 3x3 pad1) + clip.
__global__ __launch_bounds__(256) void offset_conv(const float* __restrict__ x,
                                                   const float* __restrict__ ref,
                                                   const float* __restrict__ wt,
                                                   const float* __restrict__ bias,
                                                   float* __restrict__ offs) {
    int b = blockIdx.x >> 6;
    int hp = blockIdx.x & 63;
    int tid = threadIdx.x;
    int h = hp * 2 + (tid >> 7);
    int w = tid & 127;

    float acc[NOFF];
#pragma unroll
    for (int oc = 0; oc < NOFF; ++oc) acc[oc] = bias[oc];

    for (int ci = 0; ci < 128; ++ci) {
        const float* src = (ci < Cch)
            ? (x + (size_t)(b * Cch + ci) * (Hh * Ww))
            : (ref + (size_t)(b * Cch + ci - Cch) * (Hh * Ww));
#pragma unroll
        for (int dy = 0; dy < 3; ++dy) {
            int yy = h + dy - 1;
            if ((unsigned)yy >= (unsigned)Hh) continue;
            const float* row = src + yy * Ww;
#pragma unroll
            for (int dx = 0; dx < 3; ++dx) {
                int xx = w + dx - 1;
                float v = ((unsigned)xx < (unsigned)Ww) ? row[xx] : 0.0f;
                const float* wp = wt + (ci * 9 + dy * 3 + dx) * NOFF;  // uniform -> s_load
#pragma unroll
                for (int oc = 0; oc < NOFF; ++oc)
                    acc[oc] = fmaf(v, wp[oc], acc[oc]);
            }
        }
    }

    float* op = offs + (size_t)((b * Hh + h) * Ww + w) * NOFF;
#pragma unroll
    for (int oc = 0; oc < NOFF; ++oc) {
        float v = acc[oc];
        v = fminf(fmaxf(v, -10.0f), 10.0f);
        op[oc] = v;
    }
}

// ---------------------------------------------------------------------------
// Kernel B: deformable conv with MFMA einsum.
// Block = (b, h, 16-px strip). Phase 1: bilinear samples -> bf16 LDS.
// Phase 2: wave wv computes out[wv*16..+16][px] via 18x mfma_16x16x32_bf16.
__global__ __launch_bounds__(256, 4) void deform_mfma(const float* __restrict__ x,
                                                      const unsigned short* __restrict__ wbf,
                                                      const float* __restrict__ offs,
                                                      float* __restrict__ out) {
    __shared__ float4 coords[144];                  // fy0, fx0, ty, tx per (px,tap)
    __shared__ unsigned short smp[16][CKPAD];       // [px][c*9+k] bf16

    int bi = blockIdx.x;
    int b = bi >> 10;            // 128*8 = 1024 blocks per batch
    int rem = bi & 1023;
    int h = rem >> 3;
    int w0 = (rem & 7) << 4;
    int tid = threadIdx.x;

    if (tid < 144) {
        int p = tid / 9, k = tid % 9;
        int ky = k / 3, kx = k % 3;
        const float* op = offs + (size_t)((b * Hh + h) * Ww + w0 + p) * NOFF;
        float ys = (float)(h - 1 + ky) + op[k * 2 + 0];
        float xs = (float)(w0 + p - 1 + kx) + op[k * 2 + 1];
        float fy = floorf(ys), fx = floorf(xs);
        coords[tid] = make_float4(fy, fx, ys - fy, xs - fx);
    }
    __syncthreads();

#pragma unroll 6
    for (int it = 0; it < 36; ++it) {
        int t = it * 256 + tid;          // t = c*144 + k*16 + p
        int p = t & 15;
        int k = (t >> 4) % 9;
        int c = t / 144;
        float4 cd = coords[p * 9 + k];
        int iy0 = (int)cd.x;
        int ix0 = (int)cd.y;
        float ty = cd.z, tx = cd.w;
        const float* xp = x + ((size_t)(b * Cch + c) << 14);
        int iy0c = min(max(iy0, 0), Hh - 1), iy1c = min(max(iy0 + 1, 0), Hh - 1);
        int ix0c = min(max(ix0, 0), Ww - 1), ix1c = min(max(ix0 + 1, 0), Ww - 1);
        float v00 = xp[(iy0c << 7) + ix0c];
        float v01 = xp[(iy0c << 7) + ix1c];
        float v10 = xp[(iy1c << 7) + ix0c];
        float v11 = xp[(iy1c << 7) + ix1c];
        float wy0 = (1.f - ty) * (((unsigned)iy0 < (unsigned)Hh) ? 1.f : 0.f);
        float wy1 = ty         * (((unsigned)(iy0 + 1) < (unsigned)Hh) ? 1.f : 0.f);
        float wx0 = (1.f - tx) * (((unsigned)ix0 < (unsigned)Ww) ? 1.f : 0.f);
        float wx1 = tx         * (((unsigned)(ix0 + 1) < (unsigned)Ww) ? 1.f : 0.f);
        float s = wy0 * (v00 * wx0 + v01 * wx1) + wy1 * (v10 * wx0 + v11 * wx1);
        smp[p][c * 9 + k] = f2bf(s);
    }
    __syncthreads();

    int wv = tid >> 6, lane = tid & 63;
    int r16 = lane & 15;          // A row (=o sub-index) and B col (=px)
    int g = lane >> 4;            // k-group
    floatx4 acc = {0.f, 0.f, 0.f, 0.f};
    const short8* ap = (const short8*)(wbf + (size_t)(wv * 16 + r16) * CK + g * 8);
    const unsigned short* bbase = &smp[r16][g * 8];
#pragma unroll
    for (int kk = 0; kk < 18; ++kk) {
        short8 a = ap[kk * 4];                                   // 8 bf16 of W row
        short8 bb = *(const short8*)(bbase + kk * 32);           // 8 bf16 of smp col
        acc = __builtin_amdgcn_mfma_f32_16x16x32_bf16(a, bb, acc, 0, 0, 0);
    }

    // D: col = lane&15 = px, row = g*4 + r = o sub-index
    size_t obase = ((size_t)(b * Cch + wv * 16 + g * 4)) << 14;
    int hw = (h << 7) + w0 + r16;
#pragma unroll
    for (int r = 0; r < 4; ++r)
        out[obase + ((size_t)r << 14) + hw] = acc[r];
}

// ---------------------------------------------------------------------------
extern "C" void kernel_launch(void* const* d_in, const int* in_sizes, int n_in,
                              void* d_out, int out_size, void* d_ws, size_t ws_size,
                              hipStream_t stream) {
    const float* x      = (const float*)d_in[0];
    const float* ref    = (const float*)d_in[1];
    const float* wo     = (const float*)d_in[2];
    const float* bias   = (const float*)d_in[3];
    const float* weight = (const float*)d_in[4];
    float* out = (float*)d_out;

    float* wt            = (float*)d_ws;                              // 83 KB
    float* offs          = (float*)((char*)d_ws + 131072);            // 4.5 MB
    unsigned short* wbf  = (unsigned short*)((char*)d_ws + 4980736);  // 74 KB

    hipLaunchKernelGGL(transpose_woff, dim3(81), dim3(256), 0, stream, wo, wt);
    hipLaunchKernelGGL(convert_w, dim3((Cch * CK + 255) / 256), dim3(256), 0, stream,
                       weight, wbf);
    hipLaunchKernelGGL(offset_conv, dim3(Bsz * 64), dim3(256), 0, stream,
                       x, ref, wt, bias, offs);
    hipLaunchKernelGGL(deform_mfma, dim3(Bsz * Hh * (Ww / 16)), dim3(256), 0, stream,
                       x, wbf, offs, out);
}

// Round 3
// 293.344 us; speedup vs baseline: 4.3602x; 1.1312x over previous
//
#include <hip/hip_runtime.h>

#define Bsz 4
#define Cch 64
#define Hh 128
#define Ww 128
#define NOFF 18     // 2*3*3 offset channels
#define CK 576      // 64*9 reduction length for deform einsum
#define CKPAD 584   // smp row stride in bf16 elems: 584*2B=1168B -> 2-way bank alias only

typedef __attribute__((ext_vector_type(8))) short short8;
typedef __attribute__((ext_vector_type(4))) float floatx4;

__device__ __forceinline__ unsigned short f2bf(float f) {
    union { float f; unsigned u; } v; v.f = f;
    unsigned r = v.u + 0x7fff + ((v.u >> 16) & 1);   // round-to-nearest-even
    return (unsigned short)(r >> 16);
}

// ---------------------------------------------------------------------------
// Kernel A0: transpose offset weight [oc][ci][tap] -> [ci][tap][oc]
__global__ __launch_bounds__(256) void transpose_woff(const float* __restrict__ wo,
                                                      float* __restrict__ wt) {
    int t = blockIdx.x * 256 + threadIdx.x;
    if (t >= NOFF * 128 * 9) return;
    int oc = t % NOFF;
    int rest = t / NOFF;
    int tap = rest % 9;
    int ci = rest / 9;
    wt[t] = wo[(oc * 128 + ci) * 9 + tap];
}

// Kernel A1: convert deform weight [64][576] f32 -> bf16
__global__ __launch_bounds__(256) void convert_w(const float* __restrict__ w,
                                                 unsigned short* __restrict__ wbf) {
    int t = blockIdx.x * 256 + threadIdx.x;
    if (t < Cch * CK) wbf[t] = f2bf(w[t]);
}

// ---------------------------------------------------------------------------
// Kernel A: offset conv (in=concat(x,ref) 128ch, out=18ch, 3x3 pad1) + clip.
// Block = one (b,h) row. 512 threads = 4 channel-groups x 128 pixels.
// Each group accumulates 32 input channels; LDS reduction; group 0 finalizes.
__global__ __launch_bounds__(512, 4) void offset_conv(const float* __restrict__ x,
                                                      const float* __restrict__ ref,
                                                      const float* __restrict__ wt,
                                                      const float* __restrict__ bias,
                                                      float* __restrict__ offs) {
    __shared__ float part[3][128][19];   // stride 19 floats -> 2-way bank alias (free)

    int b = blockIdx.x >> 7;
    int h = blockIdx.x & 127;
    int tid = threadIdx.x;
    int g = tid >> 7;        // channel group 0..3
    int w = tid & 127;

    float acc[NOFF];
#pragma unroll
    for (int oc = 0; oc < NOFF; ++oc) acc[oc] = 0.0f;

    for (int ci = g * 32; ci < g * 32 + 32; ++ci) {
        const float* src = (ci < Cch)
            ? (x + (size_t)(b * Cch + ci) * (Hh * Ww))
            : (ref + (size_t)(b * Cch + ci - Cch) * (Hh * Ww));
#pragma unroll
        for (int dy = 0; dy < 3; ++dy) {
            int yy = h + dy - 1;
            if ((unsigned)yy >= (unsigned)Hh) continue;
            const float* row = src + yy * Ww;
#pragma unroll
            for (int dx = 0; dx < 3; ++dx) {
                int xx = w + dx - 1;
                float v = ((unsigned)xx < (unsigned)Ww) ? row[xx] : 0.0f;
                const float* wp = wt + (ci * 9 + dy * 3 + dx) * NOFF;  // uniform -> s_load
#pragma unroll
                for (int oc = 0; oc < NOFF; ++oc)
                    acc[oc] = fmaf(v, wp[oc], acc[oc]);
            }
        }
    }

    if (g > 0) {
#pragma unroll
        for (int oc = 0; oc < NOFF; ++oc) part[g - 1][w][oc] = acc[oc];
    }
    __syncthreads();

    if (g == 0) {
#pragma unroll
        for (int g2 = 0; g2 < 3; ++g2)
#pragma unroll
            for (int oc = 0; oc < NOFF; ++oc) acc[oc] += part[g2][w][oc];

        float* op = offs + (size_t)((b * Hh + h) * Ww + w) * NOFF;
#pragma unroll
        for (int oc = 0; oc < NOFF; ++oc) {
            float v = acc[oc] + bias[oc];
            v = fminf(fmaxf(v, -10.0f), 10.0f);
            op[oc] = v;
        }
    }
}

// ---------------------------------------------------------------------------
// Kernel B: deformable conv with MFMA einsum.
// Block = (b, h, 16-px strip). Phase 1: bilinear samples -> bf16 LDS.
// Phase 2: wave wv computes out[wv*16..+16][px] via 18x mfma_16x16x32_bf16.
__global__ __launch_bounds__(256, 4) void deform_mfma(const float* __restrict__ x,
                                                      const unsigned short* __restrict__ wbf,
                                                      const float* __restrict__ offs,
                                                      float* __restrict__ out) {
    __shared__ float4 coords[144];                  // fy0, fx0, ty, tx per (px,tap)
    __shared__ unsigned short smp[16][CKPAD];       // [px][c*9+k] bf16

    int bi = blockIdx.x;
    int b = bi >> 10;            // 128*8 = 1024 blocks per batch
    int rem = bi & 1023;
    int h = rem >> 3;
    int w0 = (rem & 7) << 4;
    int tid = threadIdx.x;

    if (tid < 144) {
        int p = tid / 9, k = tid % 9;
        int ky = k / 3, kx = k % 3;
        const float* op = offs + (size_t)((b * Hh + h) * Ww + w0 + p) * NOFF;
        float ys = (float)(h - 1 + ky) + op[k * 2 + 0];
        float xs = (float)(w0 + p - 1 + kx) + op[k * 2 + 1];
        float fy = floorf(ys), fx = floorf(xs);
        coords[tid] = make_float4(fy, fx, ys - fy, xs - fx);
    }
    __syncthreads();

#pragma unroll 6
    for (int it = 0; it < 36; ++it) {
        int t = it * 256 + tid;          // t = c*144 + k*16 + p
        int p = t & 15;
        int k = (t >> 4) % 9;
        int c = t / 144;
        float4 cd = coords[p * 9 + k];
        int iy0 = (int)cd.x;
        int ix0 = (int)cd.y;
        float ty = cd.z, tx = cd.w;
        const float* xp = x + ((size_t)(b * Cch + c) << 14);
        int iy0c = min(max(iy0, 0), Hh - 1), iy1c = min(max(iy0 + 1, 0), Hh - 1);
        int ix0c = min(max(ix0, 0), Ww - 1), ix1c = min(max(ix0 + 1, 0), Ww - 1);
        float v00 = xp[(iy0c << 7) + ix0c];
        float v01 = xp[(iy0c << 7) + ix1c];
        float v10 = xp[(iy1c << 7) + ix0c];
        float v11 = xp[(iy1c << 7) + ix1c];
        float wy0 = (1.f - ty) * (((unsigned)iy0 < (unsigned)Hh) ? 1.f : 0.f);
        float wy1 = ty         * (((unsigned)(iy0 + 1) < (unsigned)Hh) ? 1.f : 0.f);
        float wx0 = (1.f - tx) * (((unsigned)ix0 < (unsigned)Ww) ? 1.f : 0.f);
        float wx1 = tx         * (((unsigned)(ix0 + 1) < (unsigned)Ww) ? 1.f : 0.f);
        float s = wy0 * (v00 * wx0 + v01 * wx1) + wy1 * (v10 * wx0 + v11 * wx1);
        smp[p][c * 9 + k] = f2bf(s);
    }
    __syncthreads();

    int wv = tid >> 6, lane = tid & 63;
    int r16 = lane & 15;          // A row (=o sub-index) and B col (=px)
    int g = lane >> 4;            // k-group
    floatx4 acc = {0.f, 0.f, 0.f, 0.f};
    const short8* ap = (const short8*)(wbf + (size_t)(wv * 16 + r16) * CK + g * 8);
    const unsigned short* bbase = &smp[r16][g * 8];
#pragma unroll
    for (int kk = 0; kk < 18; ++kk) {
        short8 a = ap[kk * 4];                                   // 8 bf16 of W row
        short8 bb = *(const short8*)(bbase + kk * 32);           // 8 bf16 of smp col
        acc = __builtin_amdgcn_mfma_f32_16x16x32_bf16(a, bb, acc, 0, 0, 0);
    }

    // D: col = lane&15 = px, row = g*4 + r = o sub-index
    size_t obase = ((size_t)(b * Cch + wv * 16 + g * 4)) << 14;
    int hw = (h << 7) + w0 + r16;
#pragma unroll
    for (int r = 0; r < 4; ++r)
        out[obase + ((size_t)r << 14) + hw] = acc[r];
}

// ---------------------------------------------------------------------------
extern "C" void kernel_launch(void* const* d_in, const int* in_sizes, int n_in,
                              void* d_out, int out_size, void* d_ws, size_t ws_size,
                              hipStream_t stream) {
    const float* x      = (const float*)d_in[0];
    const float* ref    = (const float*)d_in[1];
    const float* wo     = (const float*)d_in[2];
    const float* bias   = (const float*)d_in[3];
    const float* weight = (const float*)d_in[4];
    float* out = (float*)d_out;

    float* wt            = (float*)d_ws;                              // 83 KB
    float* offs          = (float*)((char*)d_ws + 131072);            // 4.5 MB
    unsigned short* wbf  = (unsigned short*)((char*)d_ws + 4980736);  // 74 KB

    hipLaunchKernelGGL(transpose_woff, dim3(81), dim3(256), 0, stream, wo, wt);
    hipLaunchKernelGGL(convert_w, dim3((Cch * CK + 255) / 256), dim3(256), 0, stream,
                       weight, wbf);
    hipLaunchKernelGGL(offset_conv, dim3(Bsz * Hh), dim3(512), 0, stream,
                       x, ref, wt, bias, offs);
    hipLaunchKernelGGL(deform_mfma, dim3(Bsz * Hh * (Ww / 16)), dim3(256), 0, stream,
                       x, wbf, offs, out);
}

// Round 4
// 259.399 us; speedup vs baseline: 4.9307x; 1.1309x over previous
//
#include <hip/hip_runtime.h>

#define Bsz 4
#define Cch 64
#define Hh 128
#define Ww 128
#define NOFF 18      // 2*3*3 offset channels
#define CK 576       // 64*9 reduction length for deform einsum
#define CKPAD 584    // deform smp stride (bf16): 1168B -> 2-way bank alias only
#define CKO 1152     // 128*9 reduction length for offset conv
#define CKOPAD 1160  // imcol stride (bf16): 2320B -> 2-way bank alias only

typedef __attribute__((ext_vector_type(8))) short short8;
typedef __attribute__((ext_vector_type(4))) float floatx4;

__device__ __forceinline__ unsigned short f2bf(float f) {
    union { float f; unsigned u; } v; v.f = f;
    unsigned r = v.u + 0x7fff + ((v.u >> 16) & 1);   // round-to-nearest-even
    return (unsigned short)(r >> 16);
}

// ---------------------------------------------------------------------------
// Kernel A1: convert deform weight [64][576] f32 -> bf16
__global__ __launch_bounds__(256) void convert_w(const float* __restrict__ w,
                                                 unsigned short* __restrict__ wbf) {
    int t = blockIdx.x * 256 + threadIdx.x;
    if (t < Cch * CK) wbf[t] = f2bf(w[t]);
}

// Kernel A2: convert offset weight [18][1152] f32 -> bf16, zero-pad to [32][1152]
__global__ __launch_bounds__(256) void convert_woff(const float* __restrict__ wo,
                                                    unsigned short* __restrict__ wobf) {
    int t = blockIdx.x * 256 + threadIdx.x;
    if (t >= 32 * CKO) return;
    int row = t / CKO;
    wobf[t] = (row < NOFF) ? f2bf(wo[t]) : (unsigned short)0;
}

// ---------------------------------------------------------------------------
// Kernel A: offset conv as MFMA GEMM. Block = (b, h, 16-px strip).
// Phase 1: imcol[16 px][1152] bf16 in LDS (k = ci*9 + tap, ci: 0..63 x, 64..127 ref).
// Phase 2: out[oc][px] = Woff[oc][k] * imcol[k][px]; 4 waves = 2 o-tiles x 2 K-halves,
//          18 MFMAs each; LDS-reduce K-halves; bias+clip+store f32 offs[px][18].
__global__ __launch_bounds__(256, 4) void offset_mfma(const float* __restrict__ x,
                                                      const float* __restrict__ ref,
                                                      const unsigned short* __restrict__ wobf,
                                                      const float* __restrict__ bias,
                                                      float* __restrict__ offs) {
    __shared__ unsigned short imcol[16][CKOPAD];
    __shared__ float red[2][64][4];     // K-half-1 partials per tile

    int bi = blockIdx.x;
    int b = bi >> 10;
    int rem = bi & 1023;
    int h = rem >> 3;
    int w0 = (rem & 7) << 4;
    int tid = threadIdx.x;

#pragma unroll 8
    for (int it = 0; it < 72; ++it) {
        int t = it * 256 + tid;          // t = ci*144 + tap*16 + p
        int p = t & 15;
        int tap = (t >> 4) % 9;
        int ci = t / 144;
        int dy = tap / 3, dx = tap % 3;
        int yy = h + dy - 1;
        int xx = w0 + p + dx - 1;
        const float* src = (ci < Cch)
            ? (x + ((size_t)(b * Cch + ci) << 14))
            : (ref + ((size_t)(b * Cch + ci - Cch) << 14));
        float v = ((unsigned)yy < (unsigned)Hh && (unsigned)xx < (unsigned)Ww)
                  ? src[(yy << 7) + xx] : 0.0f;
        imcol[p][ci * 9 + tap] = f2bf(v);
    }
    __syncthreads();

    int wv = tid >> 6, lane = tid & 63;
    int to = wv & 1;          // o-tile: oc base = to*16
    int kh = wv >> 1;         // K-half: k base = kh*576
    int r16 = lane & 15;      // A row / B col (px)
    int g = lane >> 4;
    floatx4 acc = {0.f, 0.f, 0.f, 0.f};
    const short8* ap = (const short8*)(wobf + (size_t)(to * 16 + r16) * CKO + kh * 576 + g * 8);
    const unsigned short* bbase = &imcol[r16][kh * 576 + g * 8];
#pragma unroll
    for (int kk = 0; kk < 18; ++kk) {
        short8 a = ap[kk * 4];
        short8 bb = *(const short8*)(bbase + kk * 32);
        acc = __builtin_amdgcn_mfma_f32_16x16x32_bf16(a, bb, acc, 0, 0, 0);
    }

    if (kh == 1) {
#pragma unroll
        for (int r = 0; r < 4; ++r) red[to][lane][r] = acc[r];
    }
    __syncthreads();
    if (kh == 0) {
#pragma unroll
        for (int r = 0; r < 4; ++r) {
            int oc = to * 16 + g * 4 + r;
            if (oc >= NOFF) break;
            float v = acc[r] + red[to][lane][r] + bias[oc];
            v = fminf(fmaxf(v, -10.0f), 10.0f);
            offs[(size_t)((b * Hh + h) * Ww + w0 + r16) * NOFF + oc] = v;
        }
    }
}

// ---------------------------------------------------------------------------
// Kernel B: deformable conv with MFMA einsum.
__global__ __launch_bounds__(256, 4) void deform_mfma(const float* __restrict__ x,
                                                      const unsigned short* __restrict__ wbf,
                                                      const float* __restrict__ offs,
                                                      float* __restrict__ out) {
    __shared__ float4 coords[144];                  // fy0, fx0, ty, tx per (px,tap)
    __shared__ unsigned short smp[16][CKPAD];       // [px][c*9+k] bf16

    int bi = blockIdx.x;
    int b = bi >> 10;
    int rem = bi & 1023;
    int h = rem >> 3;
    int w0 = (rem & 7) << 4;
    int tid = threadIdx.x;

    if (tid < 144) {
        int p = tid / 9, k = tid % 9;
        int ky = k / 3, kx = k % 3;
        const float* op = offs + (size_t)((b * Hh + h) * Ww + w0 + p) * NOFF;
        float ys = (float)(h - 1 + ky) + op[k * 2 + 0];
        float xs = (float)(w0 + p - 1 + kx) + op[k * 2 + 1];
        float fy = floorf(ys), fx = floorf(xs);
        coords[tid] = make_float4(fy, fx, ys - fy, xs - fx);
    }
    __syncthreads();

#pragma unroll 6
    for (int it = 0; it < 36; ++it) {
        int t = it * 256 + tid;          // t = c*144 + k*16 + p
        int p = t & 15;
        int k = (t >> 4) % 9;
        int c = t / 144;
        float4 cd = coords[p * 9 + k];
        int iy0 = (int)cd.x;
        int ix0 = (int)cd.y;
        float ty = cd.z, tx = cd.w;
        const float* xp = x + ((size_t)(b * Cch + c) << 14);
        int iy0c = min(max(iy0, 0), Hh - 1), iy1c = min(max(iy0 + 1, 0), Hh - 1);
        int ix0c = min(max(ix0, 0), Ww - 1), ix1c = min(max(ix0 + 1, 0), Ww - 1);
        float v00 = xp[(iy0c << 7) + ix0c];
        float v01 = xp[(iy0c << 7) + ix1c];
        float v10 = xp[(iy1c << 7) + ix0c];
        float v11 = xp[(iy1c << 7) + ix1c];
        float wy0 = (1.f - ty) * (((unsigned)iy0 < (unsigned)Hh) ? 1.f : 0.f);
        float wy1 = ty         * (((unsigned)(iy0 + 1) < (unsigned)Hh) ? 1.f : 0.f);
        float wx0 = (1.f - tx) * (((unsigned)ix0 < (unsigned)Ww) ? 1.f : 0.f);
        float wx1 = tx         * (((unsigned)(ix0 + 1) < (unsigned)Ww) ? 1.f : 0.f);
        float s = wy0 * (v00 * wx0 + v01 * wx1) + wy1 * (v10 * wx0 + v11 * wx1);
        smp[p][c * 9 + k] = f2bf(s);
    }
    __syncthreads();

    int wv = tid >> 6, lane = tid & 63;
    int r16 = lane & 15;          // A row (=o sub-index) and B col (=px)
    int g = lane >> 4;            // k-group
    floatx4 acc = {0.f, 0.f, 0.f, 0.f};
    const short8* ap = (const short8*)(wbf + (size_t)(wv * 16 + r16) * CK + g * 8);
    const unsigned short* bbase = &smp[r16][g * 8];
#pragma unroll
    for (int kk = 0; kk < 18; ++kk) {
        short8 a = ap[kk * 4];                                   // 8 bf16 of W row
        short8 bb = *(const short8*)(bbase + kk * 32);           // 8 bf16 of smp col
        acc = __builtin_amdgcn_mfma_f32_16x16x32_bf16(a, bb, acc, 0, 0, 0);
    }

    // D: col = lane&15 = px, row = g*4 + r = o sub-index
    size_t obase = ((size_t)(b * Cch + wv * 16 + g * 4)) << 14;
    int hw = (h << 7) + w0 + r16;
#pragma unroll
    for (int r = 0; r < 4; ++r)
        out[obase + ((size_t)r << 14) + hw] = acc[r];
}

// ---------------------------------------------------------------------------
extern "C" void kernel_launch(void* const* d_in, const int* in_sizes, int n_in,
                              void* d_out, int out_size, void* d_ws, size_t ws_size,
                              hipStream_t stream) {
    const float* x      = (const float*)d_in[0];
    const float* ref    = (const float*)d_in[1];
    const float* wo     = (const float*)d_in[2];
    const float* bias   = (const float*)d_in[3];
    const float* weight = (const float*)d_in[4];
    float* out = (float*)d_out;

    unsigned short* wobf = (unsigned short*)d_ws;                     // 32*1152*2 = 72 KB
    float* offs          = (float*)((char*)d_ws + 131072);            // 4.5 MB
    unsigned short* wbf  = (unsigned short*)((char*)d_ws + 4980736);  // 74 KB

    hipLaunchKernelGGL(convert_w, dim3((Cch * CK + 255) / 256), dim3(256), 0, stream,
                       weight, wbf);
    hipLaunchKernelGGL(convert_woff, dim3((32 * CKO + 255) / 256), dim3(256), 0, stream,
                       wo, wobf);
    hipLaunchKernelGGL(offset_mfma, dim3(Bsz * Hh * (Ww / 16)), dim3(256), 0, stream,
                       x, ref, wobf, bias, offs);
    hipLaunchKernelGGL(deform_mfma, dim3(Bsz * Hh * (Ww / 16)), dim3(256), 0, stream,
                       x, wbf, offs, out);
}

// Round 5
// 177.975 us; speedup vs baseline: 7.1866x; 1.4575x over previous
//
#include <hip/hip_runtime.h>

#define Bsz 4
#define Cch 64
#define Hh 128
#define Ww 128
#define NOFF 18      // 2*3*3 offset channels
#define CK 576       // 64*9 reduction length for deform einsum
#define CKPAD 584    // deform smp stride (bf16): 1168B -> 2-way bank alias only

typedef __attribute__((ext_vector_type(8))) short short8;
typedef __attribute__((ext_vector_type(4))) float floatx4;

__device__ __forceinline__ unsigned short f2bf(float f) {
    union { float f; unsigned u; } v; v.f = f;
    unsigned r = v.u + 0x7fff + ((v.u >> 16) & 1);   // round-to-nearest-even
    return (unsigned short)(r >> 16);
}

// ---------------------------------------------------------------------------
// Kernel A1: convert deform weight [64][576] f32 -> bf16
__global__ __launch_bounds__(256) void convert_w(const float* __restrict__ w,
                                                 unsigned short* __restrict__ wbf) {
    int t = blockIdx.x * 256 + threadIdx.x;
    if (t < Cch * CK) wbf[t] = f2bf(w[t]);
}

// Kernel A2: offset weight wo[oc][ci][tap] -> w9[tap][32 oc (pad)][128 ci] bf16
__global__ __launch_bounds__(256) void convert_w9(const float* __restrict__ wo,
                                                  unsigned short* __restrict__ w9) {
    int t = blockIdx.x * 256 + threadIdx.x;
    if (t >= 9 * 32 * 128) return;
    int ci = t & 127;
    int ocp = (t >> 7) & 31;
    int tap = t >> 12;
    w9[t] = (ocp < NOFF) ? f2bf(wo[(ocp * 128 + ci) * 9 + tap]) : (unsigned short)0;
}

// ---------------------------------------------------------------------------
// Kernel A: offset conv as 9 tap-shifted MFMA GEMMs. Block = (b, h, 16-px strip).
// Phase 1: raw tile[3 rows][18 cols][128 ci] bf16 in LDS, ci XOR-swizzled by
//          (xx&7)<<3 so stride-256B column reads are only 2-way bank-aliased.
// Phase 2: 4 waves = 2 oc-tiles x 2 ci-halves; per wave 9 taps x 2 MFMAs;
//          LDS-reduce ci-halves; bias+clip+store f32 offs[px][18].
__global__ __launch_bounds__(256, 8) void offset_mfma(const float* __restrict__ x,
                                                      const float* __restrict__ ref,
                                                      const unsigned short* __restrict__ w9,
                                                      const float* __restrict__ bias,
                                                      float* __restrict__ offs) {
    __shared__ unsigned short tile[3 * 18 * 128];   // 13.5 KB
    __shared__ float red[2][64][4];                 // 2 KB

    int bi = blockIdx.x;
    int b = bi >> 10;
    int rem = bi & 1023;
    int h = rem >> 3;
    int w0 = (rem & 7) << 4;
    int tid = threadIdx.x;

    // Phase 1: stage raw strip. 1728 items = (ciq 0..31) x (row 0..2) x (xx 0..17),
    // xx fastest across lanes -> coalesced 18-wide runs; 4 ci per item -> b64 write.
#pragma unroll
    for (int it = 0; it < 7; ++it) {
        int idx = it * 256 + tid;
        if (idx < 1728) {
            int xx = idx % 18;
            int rest = idx / 18;
            int row = rest % 3;
            int ciq = rest / 3;
            int ci0 = ciq << 2;
            int yy = h + row - 1;
            int xg = w0 + xx - 1;
            const float* src = (ci0 < Cch)
                ? (x + ((size_t)(b * Cch + ci0) << 14))
                : (ref + ((size_t)(b * Cch + ci0 - Cch) << 14));
            float v0 = 0.f, v1 = 0.f, v2 = 0.f, v3 = 0.f;
            if ((unsigned)yy < (unsigned)Hh && (unsigned)xg < (unsigned)Ww) {
                const float* p = src + (yy << 7) + xg;
                v0 = p[0]; v1 = p[1 << 14]; v2 = p[2 << 14]; v3 = p[3 << 14];
            }
            unsigned lo = (unsigned)f2bf(v0) | ((unsigned)f2bf(v1) << 16);
            unsigned hi = (unsigned)f2bf(v2) | ((unsigned)f2bf(v3) << 16);
            int slot = (row * 18 + xx) * 128 + (ci0 ^ ((xx & 7) << 3));
            *(uint2*)(&tile[slot]) = make_uint2(lo, hi);
        }
    }
    __syncthreads();

    // Phase 2
    int wv = tid >> 6, lane = tid & 63;
    int to = wv & 1;          // oc tile: base = to*16
    int kh = wv >> 1;         // ci half: base = kh*64 (0: x, 1: ref)
    int r16 = lane & 15;      // A row (oc) / B col (px)
    int g = lane >> 4;        // k-group
    floatx4 acc = {0.f, 0.f, 0.f, 0.f};

#pragma unroll
    for (int tap = 0; tap < 9; ++tap) {
        int dy = tap / 3, dx = tap % 3;
        int xxr = r16 + dx;                              // 0..17
        const unsigned short* brow = &tile[(dy * 18 + xxr) * 128];
        int sw = (xxr & 7) << 3;
        const unsigned short* arow = w9 + ((size_t)(tap * 32 + to * 16 + r16) << 7) + kh * 64;
#pragma unroll
        for (int kk = 0; kk < 2; ++kk) {
            int cb = kh * 64 + kk * 32 + g * 8;
            short8 bb = *(const short8*)(brow + (cb ^ sw));
            short8 a = *(const short8*)(arow + kk * 32 + g * 8);
            acc = __builtin_amdgcn_mfma_f32_16x16x32_bf16(a, bb, acc, 0, 0, 0);
        }
    }

    if (kh == 1) {
#pragma unroll
        for (int r = 0; r < 4; ++r) red[to][lane][r] = acc[r];
    }
    __syncthreads();
    if (kh == 0) {
#pragma unroll
        for (int r = 0; r < 4; ++r) {
            int oc = to * 16 + g * 4 + r;
            if (oc >= NOFF) break;
            float v = acc[r] + red[to][lane][r] + bias[oc];
            v = fminf(fmaxf(v, -10.0f), 10.0f);
            offs[(size_t)((b * Hh + h) * Ww + w0 + r16) * NOFF + oc] = v;
        }
    }
}

// ---------------------------------------------------------------------------
// Kernel B: deformable conv with MFMA einsum.
__global__ __launch_bounds__(256, 8) void deform_mfma(const float* __restrict__ x,
                                                      const unsigned short* __restrict__ wbf,
                                                      const float* __restrict__ offs,
                                                      float* __restrict__ out) {
    __shared__ float4 coords[144];                  // fy0, fx0, ty, tx per (px,tap)
    __shared__ unsigned short smp[16][CKPAD];       // [px][c*9+k] bf16

    int bi = blockIdx.x;
    int b = bi >> 10;
    int rem = bi & 1023;
    int h = rem >> 3;
    int w0 = (rem & 7) << 4;
    int tid = threadIdx.x;

    if (tid < 144) {
        int p = tid / 9, k = tid % 9;
        int ky = k / 3, kx = k % 3;
        const float* op = offs + (size_t)((b * Hh + h) * Ww + w0 + p) * NOFF;
        float ys = (float)(h - 1 + ky) + op[k * 2 + 0];
        float xs = (float)(w0 + p - 1 + kx) + op[k * 2 + 1];
        float fy = floorf(ys), fx = floorf(xs);
        coords[tid] = make_float4(fy, fx, ys - fy, xs - fx);
    }
    __syncthreads();

#pragma unroll 6
    for (int it = 0; it < 36; ++it) {
        int t = it * 256 + tid;          // t = c*144 + k*16 + p
        int p = t & 15;
        int k = (t >> 4) % 9;
        int c = t / 144;
        float4 cd = coords[p * 9 + k];
        int iy0 = (int)cd.x;
        int ix0 = (int)cd.y;
        float ty = cd.z, tx = cd.w;
        const float* xp = x + ((size_t)(b * Cch + c) << 14);
        int iy0c = min(max(iy0, 0), Hh - 1), iy1c = min(max(iy0 + 1, 0), Hh - 1);
        int ix0c = min(max(ix0, 0), Ww - 1), ix1c = min(max(ix0 + 1, 0), Ww - 1);
        float v00 = xp[(iy0c << 7) + ix0c];
        float v01 = xp[(iy0c << 7) + ix1c];
        float v10 = xp[(iy1c << 7) + ix0c];
        float v11 = xp[(iy1c << 7) + ix1c];
        float wy0 = (1.f - ty) * (((unsigned)iy0 < (unsigned)Hh) ? 1.f : 0.f);
        float wy1 = ty         * (((unsigned)(iy0 + 1) < (unsigned)Hh) ? 1.f : 0.f);
        float wx0 = (1.f - tx) * (((unsigned)ix0 < (unsigned)Ww) ? 1.f : 0.f);
        float wx1 = tx         * (((unsigned)(ix0 + 1) < (unsigned)Ww) ? 1.f : 0.f);
        float s = wy0 * (v00 * wx0 + v01 * wx1) + wy1 * (v10 * wx0 + v11 * wx1);
        smp[p][c * 9 + k] = f2bf(s);
    }
    __syncthreads();

    int wv = tid >> 6, lane = tid & 63;
    int r16 = lane & 15;          // A row (=o sub-index) and B col (=px)
    int g = lane >> 4;            // k-group
    floatx4 acc = {0.f, 0.f, 0.f, 0.f};
    const short8* ap = (const short8*)(wbf + (size_t)(wv * 16 + r16) * CK + g * 8);
    const unsigned short* bbase = &smp[r16][g * 8];
#pragma unroll
    for (int kk = 0; kk < 18; ++kk) {
        short8 a = ap[kk * 4];                                   // 8 bf16 of W row
        short8 bb = *(const short8*)(bbase + kk * 32);           // 8 bf16 of smp col
        acc = __builtin_amdgcn_mfma_f32_16x16x32_bf16(a, bb, acc, 0, 0, 0);
    }

    // D: col = lane&15 = px, row = g*4 + r = o sub-index
    size_t obase = ((size_t)(b * Cch + wv * 16 + g * 4)) << 14;
    int hw = (h << 7) + w0 + r16;
#pragma unroll
    for (int r = 0; r < 4; ++r)
        out[obase + ((size_t)r << 14) + hw] = acc[r];
}

// ---------------------------------------------------------------------------
extern "C" void kernel_launch(void* const* d_in, const int* in_sizes, int n_in,
                              void* d_out, int out_size, void* d_ws, size_t ws_size,
                              hipStream_t stream) {
    const float* x      = (const float*)d_in[0];
    const float* ref    = (const float*)d_in[1];
    const float* wo     = (const float*)d_in[2];
    const float* bias   = (const float*)d_in[3];
    const float* weight = (const float*)d_in[4];
    float* out = (float*)d_out;

    unsigned short* w9  = (unsigned short*)d_ws;                      // 9*32*128*2 = 72 KB
    float* offs         = (float*)((char*)d_ws + 262144);             // 4.5 MB
    unsigned short* wbf = (unsigned short*)((char*)d_ws + 5111808);   // 72 KB

    hipLaunchKernelGGL(convert_w, dim3((Cch * CK + 255) / 256), dim3(256), 0, stream,
                       weight, wbf);
    hipLaunchKernelGGL(convert_w9, dim3((9 * 32 * 128 + 255) / 256), dim3(256), 0, stream,
                       wo, w9);
    hipLaunchKernelGGL(offset_mfma, dim3(Bsz * Hh * (Ww / 16)), dim3(256), 0, stream,
                       x, ref, w9, bias, offs);
    hipLaunchKernelGGL(deform_mfma, dim3(Bsz * Hh * (Ww / 16)), dim3(256), 0, stream,
                       x, wbf, offs, out);
}

// Round 6
// 156.641 us; speedup vs baseline: 8.1653x; 1.1362x over previous
//
#include <hip/hip_runtime.h>

#define Bsz 4
#define Cch 64
#define Hh 128
#define Ww 128
#define NOFF 18      // 2*3*3 offset channels
#define CK 576       // 64*9 reduction length for deform einsum (K = k*64 + c)
#define CKPAD 580    // smp row stride (bf16): 1160B -> conflict-free r/w patterns

typedef __attribute__((ext_vector_type(8))) short short8;
typedef __attribute__((ext_vector_type(4))) float floatx4;

__device__ __forceinline__ unsigned short f2bf(float f) {
    union { float f; unsigned u; } v; v.f = f;
    unsigned r = v.u + 0x7fff + ((v.u >> 16) & 1);   // round-to-nearest-even
    return (unsigned short)(r >> 16);
}

// ---------------------------------------------------------------------------
// Kernel A1: deform weight w[oc][c][tap] f32 -> wbf[oc][tap*64 + c] bf16
// (K-order tap-major/channel-minor to match smp quad writes)
__global__ __launch_bounds__(256) void convert_w(const float* __restrict__ w,
                                                 unsigned short* __restrict__ wbf) {
    int t = blockIdx.x * 256 + threadIdx.x;
    if (t >= Cch * CK) return;
    int oc = t / CK;
    int rem = t % CK;
    int k = rem >> 6;
    int c = rem & 63;
    wbf[t] = f2bf(w[(oc * Cch + c) * 9 + k]);
}

// Kernel A2: offset weight wo[oc][ci][tap] -> w9[tap][32 oc (pad)][128 ci] bf16
__global__ __launch_bounds__(256) void convert_w9(const float* __restrict__ wo,
                                                  unsigned short* __restrict__ w9) {
    int t = blockIdx.x * 256 + threadIdx.x;
    if (t >= 9 * 32 * 128) return;
    int ci = t & 127;
    int ocp = (t >> 7) & 31;
    int tap = t >> 12;
    w9[t] = (ocp < NOFF) ? f2bf(wo[(ocp * 128 + ci) * 9 + tap]) : (unsigned short)0;
}

// ---------------------------------------------------------------------------
// Kernel A: offset conv as 9 tap-shifted MFMA GEMMs. Block = (b, h, 16-px strip).
__global__ __launch_bounds__(256, 8) void offset_mfma(const float* __restrict__ x,
                                                      const float* __restrict__ ref,
                                                      const unsigned short* __restrict__ w9,
                                                      const float* __restrict__ bias,
                                                      float* __restrict__ offs) {
    __shared__ unsigned short tile[3 * 18 * 128];   // 13.5 KB
    __shared__ float red[2][64][4];                 // 2 KB

    int bi = blockIdx.x;
    int b = bi >> 10;
    int rem = bi & 1023;
    int h = rem >> 3;
    int w0 = (rem & 7) << 4;
    int tid = threadIdx.x;

#pragma unroll
    for (int it = 0; it < 7; ++it) {
        int idx = it * 256 + tid;
        if (idx < 1728) {
            int xx = idx % 18;
            int rest = idx / 18;
            int row = rest % 3;
            int ciq = rest / 3;
            int ci0 = ciq << 2;
            int yy = h + row - 1;
            int xg = w0 + xx - 1;
            const float* src = (ci0 < Cch)
                ? (x + ((size_t)(b * Cch + ci0) << 14))
                : (ref + ((size_t)(b * Cch + ci0 - Cch) << 14));
            float v0 = 0.f, v1 = 0.f, v2 = 0.f, v3 = 0.f;
            if ((unsigned)yy < (unsigned)Hh && (unsigned)xg < (unsigned)Ww) {
                const float* p = src + (yy << 7) + xg;
                v0 = p[0]; v1 = p[1 << 14]; v2 = p[2 << 14]; v3 = p[3 << 14];
            }
            unsigned lo = (unsigned)f2bf(v0) | ((unsigned)f2bf(v1) << 16);
            unsigned hi = (unsigned)f2bf(v2) | ((unsigned)f2bf(v3) << 16);
            int slot = (row * 18 + xx) * 128 + (ci0 ^ ((xx & 7) << 3));
            *(uint2*)(&tile[slot]) = make_uint2(lo, hi);
        }
    }
    __syncthreads();

    int wv = tid >> 6, lane = tid & 63;
    int to = wv & 1;          // oc tile: base = to*16
    int kh = wv >> 1;         // ci half: base = kh*64 (0: x, 1: ref)
    int r16 = lane & 15;      // A row (oc) / B col (px)
    int g = lane >> 4;        // k-group
    floatx4 acc = {0.f, 0.f, 0.f, 0.f};

#pragma unroll
    for (int tap = 0; tap < 9; ++tap) {
        int dy = tap / 3, dx = tap % 3;
        int xxr = r16 + dx;                              // 0..17
        const unsigned short* brow = &tile[(dy * 18 + xxr) * 128];
        int sw = (xxr & 7) << 3;
        const unsigned short* arow = w9 + ((size_t)(tap * 32 + to * 16 + r16) << 7) + kh * 64;
#pragma unroll
        for (int kk = 0; kk < 2; ++kk) {
            int cb = kh * 64 + kk * 32 + g * 8;
            short8 bb = *(const short8*)(brow + (cb ^ sw));
            short8 a = *(const short8*)(arow + kk * 32 + g * 8);
            acc = __builtin_amdgcn_mfma_f32_16x16x32_bf16(a, bb, acc, 0, 0, 0);
        }
    }

    if (kh == 1) {
#pragma unroll
        for (int r = 0; r < 4; ++r) red[to][lane][r] = acc[r];
    }
    __syncthreads();
    if (kh == 0) {
#pragma unroll
        for (int r = 0; r < 4; ++r) {
            int oc = to * 16 + g * 4 + r;
            if (oc >= NOFF) break;
            float v = acc[r] + red[to][lane][r] + bias[oc];
            v = fminf(fmaxf(v, -10.0f), 10.0f);
            offs[(size_t)((b * Hh + h) * Ww + w0 + r16) * NOFF + oc] = v;
        }
    }
}

// ---------------------------------------------------------------------------
// Kernel B: deformable conv with MFMA einsum.
// Setup: per (px,tap) fold bilinear masks+selects into 4 corner weights
//        (A,B,C,D) + 2 clamped row byte-offsets.
// Phase 1: thread = (px, c-quad); per tap: 1 wts + 1 meta LDS read serves
//          4 channels x (4 dword loads + 4 FMA); one ds_write_b64 per tap.
// Phase 2: wave wv -> out channels [wv*16, +16); 18x mfma_16x16x32_bf16.
__global__ __launch_bounds__(256, 7) void deform_mfma(const float* __restrict__ x,
                                                      const unsigned short* __restrict__ wbf,
                                                      const float* __restrict__ offs,
                                                      float* __restrict__ out) {
    __shared__ float4 wts[144];                 // A,B,C,D corner weights
    __shared__ int2 meta[144];                  // row0/row1 byte offsets (clamped)
    __shared__ unsigned short smp[16][CKPAD];   // [px][k*64+c] bf16

    int bi = blockIdx.x;
    int b = bi >> 10;
    int rem = bi & 1023;
    int h = rem >> 3;
    int w0 = (rem & 7) << 4;
    int tid = threadIdx.x;

    if (tid < 144) {
        int p = tid / 9, k = tid % 9;
        int ky = k / 3, kx = k % 3;
        const float* op = offs + (size_t)((b * Hh + h) * Ww + w0 + p) * NOFF;
        float ys = (float)(h - 1 + ky) + op[k * 2 + 0];
        float xs = (float)(w0 + p - 1 + kx) + op[k * 2 + 1];
        float fy = floorf(ys), fx = floorf(xs);
        int iy0 = (int)fy, ix0 = (int)fx;
        float ty = ys - fy, tx = xs - fx;
        float wy0 = (1.f - ty) * (((unsigned)iy0 < (unsigned)Hh) ? 1.f : 0.f);
        float wy1 = ty         * (((unsigned)(iy0 + 1) < (unsigned)Hh) ? 1.f : 0.f);
        float wx0 = (1.f - tx) * (((unsigned)ix0 < (unsigned)Ww) ? 1.f : 0.f);
        float wx1 = tx         * (((unsigned)(ix0 + 1) < (unsigned)Ww) ? 1.f : 0.f);
        int ixb  = min(max(ix0, 0), Ww - 2);          // pair base: loads [ixb, ixb+1]
        int iy0c = min(max(iy0, 0), Hh - 1);
        int iy1c = min(max(iy0 + 1, 0), Hh - 1);
        int ix0c = min(max(ix0, 0), Ww - 1);
        int ix1c = min(max(ix0 + 1, 0), Ww - 1);
        bool s0 = (ix0c != ixb);                      // corner x0 maps to ixb+1
        bool s1 = (ix1c != ixb);                      // corner x1 maps to ixb+1
        float w00 = wy0 * wx0, w01 = wy0 * wx1, w10 = wy1 * wx0, w11 = wy1 * wx1;
        float A = (s0 ? 0.f : w00) + (s1 ? 0.f : w01);   // weight of x[y0][ixb]
        float Bw = (s0 ? w00 : 0.f) + (s1 ? w01 : 0.f);  // weight of x[y0][ixb+1]
        float Cw = (s0 ? 0.f : w10) + (s1 ? 0.f : w11);  // weight of x[y1][ixb]
        float Dw = (s0 ? w10 : 0.f) + (s1 ? w11 : 0.f);  // weight of x[y1][ixb+1]
        wts[tid] = make_float4(A, Bw, Cw, Dw);
        meta[tid] = make_int2(((iy0c << 7) + ixb) << 2, ((iy1c << 7) + ixb) << 2);
    }
    __syncthreads();

    {
        int p = tid & 15;          // pixel
        int cq = tid >> 4;         // channel quad 0..15
        const char* plane0 = (const char*)(x + ((size_t)(b * Cch + cq * 4) << 14));
#pragma unroll 3
        for (int k = 0; k < 9; ++k) {
            float4 wt4 = wts[p * 9 + k];
            int2 mm = meta[p * 9 + k];
            unsigned pk[4];
#pragma unroll
            for (int cc = 0; cc < 4; ++cc) {
                const char* pl = plane0 + (cc << 16);
                const float* r0 = (const float*)(pl + mm.x);
                const float* r1 = (const float*)(pl + mm.y);
                float s = r0[0] * wt4.x + r0[1] * wt4.y + r1[0] * wt4.z + r1[1] * wt4.w;
                pk[cc] = f2bf(s);
            }
            *(uint2*)(&smp[p][k * 64 + cq * 4]) =
                make_uint2(pk[0] | (pk[1] << 16), pk[2] | (pk[3] << 16));
        }
    }
    __syncthreads();

    int wv = tid >> 6, lane = tid & 63;
    int r16 = lane & 15;          // A row (=o sub-index) and B col (=px)
    int g = lane >> 4;            // k-group
    floatx4 acc = {0.f, 0.f, 0.f, 0.f};
    const short8* ap = (const short8*)(wbf + (size_t)(wv * 16 + r16) * CK + g * 8);
    const unsigned short* bbase = &smp[r16][g * 8];
#pragma unroll
    for (int kk = 0; kk < 18; ++kk) {
        short8 a = ap[kk * 4];                                   // 8 bf16 of W row
        short8 bb = *(const short8*)(bbase + kk * 32);           // 8 bf16 of smp col
        acc = __builtin_amdgcn_mfma_f32_16x16x32_bf16(a, bb, acc, 0, 0, 0);
    }

    // D: col = lane&15 = px, row = g*4 + r = o sub-index
    size_t obase = ((size_t)(b * Cch + wv * 16 + g * 4)) << 14;
    int hw = (h << 7) + w0 + r16;
#pragma unroll
    for (int r = 0; r < 4; ++r)
        out[obase + ((size_t)r << 14) + hw] = acc[r];
}

// ---------------------------------------------------------------------------
extern "C" void kernel_launch(void* const* d_in, const int* in_sizes, int n_in,
                              void* d_out, int out_size, void* d_ws, size_t ws_size,
                              hipStream_t stream) {
    const float* x      = (const float*)d_in[0];
    const float* ref    = (const float*)d_in[1];
    const float* wo     = (const float*)d_in[2];
    const float* bias   = (const float*)d_in[3];
    const float* weight = (const float*)d_in[4];
    float* out = (float*)d_out;

    unsigned short* w9  = (unsigned short*)d_ws;                      // 72 KB
    float* offs         = (float*)((char*)d_ws + 262144);             // 4.5 MB
    unsigned short* wbf = (unsigned short*)((char*)d_ws + 5111808);   // 72 KB

    hipLaunchKernelGGL(convert_w, dim3((Cch * CK + 255) / 256), dim3(256), 0, stream,
                       weight, wbf);
    hipLaunchKernelGGL(convert_w9, dim3((9 * 32 * 128 + 255) / 256), dim3(256), 0, stream,
                       wo, w9);
    hipLaunchKernelGGL(offset_mfma, dim3(Bsz * Hh * (Ww / 16)), dim3(256), 0, stream,
                       x, ref, w9, bias, offs);
    hipLaunchKernelGGL(deform_mfma, dim3(Bsz * Hh * (Ww / 16)), dim3(256), 0, stream,
                       x, wbf, offs, out);
}

// Round 7
// 120.798 us; speedup vs baseline: 10.5881x; 1.2967x over previous
//
#include <hip/hip_runtime.h>

#define Bsz 4
#define Cch 64
#define Hh 128
#define Ww 128
#define NOFF 18      // 2*3*3 offset channels
#define CK 576       // 64*9 reduction length for deform einsum (K = k*64 + c)
#define CKPAD 580    // smp row stride (bf16): 1160B -> conflict-free r/w patterns

typedef __attribute__((ext_vector_type(8))) short short8;
typedef __attribute__((ext_vector_type(4))) float floatx4;

__device__ __forceinline__ unsigned short f2bf(float f) {
    union { float f; unsigned u; } v; v.f = f;
    unsigned r = v.u + 0x7fff + ((v.u >> 16) & 1);   // round-to-nearest-even
    return (unsigned short)(r >> 16);
}
__device__ __forceinline__ float bflo(unsigned d) {
    union { unsigned u; float f; } v; v.u = d << 16; return v.f;
}
__device__ __forceinline__ float bfhi(unsigned d) {
    union { unsigned u; float f; } v; v.u = d & 0xffff0000u; return v.f;
}

// ---------------------------------------------------------------------------
// Kernel A1: deform weight w[oc][c][tap] f32 -> wbf[oc][tap*64 + c] bf16
__global__ __launch_bounds__(256) void convert_w(const float* __restrict__ w,
                                                 unsigned short* __restrict__ wbf) {
    int t = blockIdx.x * 256 + threadIdx.x;
    if (t >= Cch * CK) return;
    int oc = t / CK;
    int rem = t % CK;
    int k = rem >> 6;
    int c = rem & 63;
    wbf[t] = f2bf(w[(oc * Cch + c) * 9 + k]);
}

// Kernel A2: offset weight wo[oc][ci][tap] -> w9[tap][32 oc (pad)][128 ci] bf16
__global__ __launch_bounds__(256) void convert_w9(const float* __restrict__ wo,
                                                  unsigned short* __restrict__ w9) {
    int t = blockIdx.x * 256 + threadIdx.x;
    if (t >= 9 * 32 * 128) return;
    int ci = t & 127;
    int ocp = (t >> 7) & 31;
    int tap = t >> 12;
    w9[t] = (ocp < NOFF) ? f2bf(wo[(ocp * 128 + ci) * 9 + tap]) : (unsigned short)0;
}

// Kernel A3: transpose x[b][c][h][w] f32 -> xtr[b][h*w][64 c] bf16 (channel-minor)
__global__ __launch_bounds__(256) void transpose_x(const float* __restrict__ x,
                                                   unsigned short* __restrict__ xtr) {
    __shared__ unsigned short tile[64][66];   // 66 stride -> odd dword stride, ~2-way
    int blk = blockIdx.x;                     // b = blk>>8, hw0 = (blk&255)*64
    int b = blk >> 8;
    int hw0 = (blk & 255) << 6;
    int tid = threadIdx.x;
    int px = tid & 63, cg = tid >> 6;         // cg: 16 channels each
    const float* src = x + ((size_t)b << 20) + hw0 + px;
#pragma unroll
    for (int i = 0; i < 16; ++i) {
        int c = cg * 16 + i;
        tile[px][c] = f2bf(src[(size_t)c << 14]);   // 64-lane coalesced per c
    }
    __syncthreads();
    int p2 = tid >> 4, cq = tid & 15;
#pragma unroll
    for (int j = 0; j < 4; ++j) {
        int px2 = j * 16 + p2;
        uint2 v = make_uint2(
            (unsigned)tile[px2][cq * 4 + 0] | ((unsigned)tile[px2][cq * 4 + 1] << 16),
            (unsigned)tile[px2][cq * 4 + 2] | ((unsigned)tile[px2][cq * 4 + 3] << 16));
        *(uint2*)(xtr + ((size_t)b << 20) + ((size_t)(hw0 + px2) << 6) + cq * 4) = v;
    }
}

// ---------------------------------------------------------------------------
// Kernel A: offset conv as 9 tap-shifted MFMA GEMMs. Block = (b, h, 16-px strip).
__global__ __launch_bounds__(256, 8) void offset_mfma(const float* __restrict__ x,
                                                      const float* __restrict__ ref,
                                                      const unsigned short* __restrict__ w9,
                                                      const float* __restrict__ bias,
                                                      float* __restrict__ offs) {
    __shared__ unsigned short tile[3 * 18 * 128];   // 13.5 KB
    __shared__ float red[2][64][4];                 // 2 KB

    int bi = blockIdx.x;
    int b = bi >> 10;
    int rem = bi & 1023;
    int h = rem >> 3;
    int w0 = (rem & 7) << 4;
    int tid = threadIdx.x;

#pragma unroll
    for (int it = 0; it < 7; ++it) {
        int idx = it * 256 + tid;
        if (idx < 1728) {
            int xx = idx % 18;
            int rest = idx / 18;
            int row = rest % 3;
            int ciq = rest / 3;
            int ci0 = ciq << 2;
            int yy = h + row - 1;
            int xg = w0 + xx - 1;
            const float* src = (ci0 < Cch)
                ? (x + ((size_t)(b * Cch + ci0) << 14))
                : (ref + ((size_t)(b * Cch + ci0 - Cch) << 14));
            float v0 = 0.f, v1 = 0.f, v2 = 0.f, v3 = 0.f;
            if ((unsigned)yy < (unsigned)Hh && (unsigned)xg < (unsigned)Ww) {
                const float* p = src + (yy << 7) + xg;
                v0 = p[0]; v1 = p[1 << 14]; v2 = p[2 << 14]; v3 = p[3 << 14];
            }
            unsigned lo = (unsigned)f2bf(v0) | ((unsigned)f2bf(v1) << 16);
            unsigned hi = (unsigned)f2bf(v2) | ((unsigned)f2bf(v3) << 16);
            int slot = (row * 18 + xx) * 128 + (ci0 ^ ((xx & 7) << 3));
            *(uint2*)(&tile[slot]) = make_uint2(lo, hi);
        }
    }
    __syncthreads();

    int wv = tid >> 6, lane = tid & 63;
    int to = wv & 1;          // oc tile: base = to*16
    int kh = wv >> 1;         // ci half: base = kh*64 (0: x, 1: ref)
    int r16 = lane & 15;      // A row (oc) / B col (px)
    int g = lane >> 4;        // k-group
    floatx4 acc = {0.f, 0.f, 0.f, 0.f};

#pragma unroll
    for (int tap = 0; tap < 9; ++tap) {
        int dy = tap / 3, dx = tap % 3;
        int xxr = r16 + dx;                              // 0..17
        const unsigned short* brow = &tile[(dy * 18 + xxr) * 128];
        int sw = (xxr & 7) << 3;
        const unsigned short* arow = w9 + ((size_t)(tap * 32 + to * 16 + r16) << 7) + kh * 64;
#pragma unroll
        for (int kk = 0; kk < 2; ++kk) {
            int cb = kh * 64 + kk * 32 + g * 8;
            short8 bb = *(const short8*)(brow + (cb ^ sw));
            short8 a = *(const short8*)(arow + kk * 32 + g * 8);
            acc = __builtin_amdgcn_mfma_f32_16x16x32_bf16(a, bb, acc, 0, 0, 0);
        }
    }

    if (kh == 1) {
#pragma unroll
        for (int r = 0; r < 4; ++r) red[to][lane][r] = acc[r];
    }
    __syncthreads();
    if (kh == 0) {
#pragma unroll
        for (int r = 0; r < 4; ++r) {
            int oc = to * 16 + g * 4 + r;
            if (oc >= NOFF) break;
            float v = acc[r] + red[to][lane][r] + bias[oc];
            v = fminf(fmaxf(v, -10.0f), 10.0f);
            offs[(size_t)((b * Hh + h) * Ww + w0 + r16) * NOFF + oc] = v;
        }
    }
}

// ---------------------------------------------------------------------------
// Kernel B: deformable conv with MFMA einsum, sampling from channel-minor xtr.
// Phase 1: thread = (p = tid>>4, cq = tid&15). Per tap: wts/meta broadcast
//          (16 lanes same p); 4 corner loads are consecutive 8B chunks of
//          contiguous 128B channel-runs -> coalesced; one ds_write_b64.
// Phase 2: wave wv -> out channels [wv*16, +16); 18x mfma_16x16x32_bf16.
__global__ __launch_bounds__(256, 7) void deform_mfma(const unsigned short* __restrict__ xtr,
                                                      const unsigned short* __restrict__ wbf,
                                                      const float* __restrict__ offs,
                                                      float* __restrict__ out) {
    __shared__ float4 wts[144];                 // A,B,C,D corner weights
    __shared__ int2 meta[144];                  // row0/row1 position byte offsets
    __shared__ unsigned short smp[16][CKPAD];   // [px][k*64+c] bf16

    int bi = blockIdx.x;
    int b = bi >> 10;
    int rem = bi & 1023;
    int h = rem >> 3;
    int w0 = (rem & 7) << 4;
    int tid = threadIdx.x;

    if (tid < 144) {
        int p = tid / 9, k = tid % 9;
        int ky = k / 3, kx = k % 3;
        const float* op = offs + (size_t)((b * Hh + h) * Ww + w0 + p) * NOFF;
        float ys = (float)(h - 1 + ky) + op[k * 2 + 0];
        float xs = (float)(w0 + p - 1 + kx) + op[k * 2 + 1];
        float fy = floorf(ys), fx = floorf(xs);
        int iy0 = (int)fy, ix0 = (int)fx;
        float ty = ys - fy, tx = xs - fx;
        float wy0 = (1.f - ty) * (((unsigned)iy0 < (unsigned)Hh) ? 1.f : 0.f);
        float wy1 = ty         * (((unsigned)(iy0 + 1) < (unsigned)Hh) ? 1.f : 0.f);
        float wx0 = (1.f - tx) * (((unsigned)ix0 < (unsigned)Ww) ? 1.f : 0.f);
        float wx1 = tx         * (((unsigned)(ix0 + 1) < (unsigned)Ww) ? 1.f : 0.f);
        int ixb  = min(max(ix0, 0), Ww - 2);          // pair base: [ixb, ixb+1]
        int iy0c = min(max(iy0, 0), Hh - 1);
        int iy1c = min(max(iy0 + 1, 0), Hh - 1);
        int ix0c = min(max(ix0, 0), Ww - 1);
        int ix1c = min(max(ix0 + 1, 0), Ww - 1);
        bool s0 = (ix0c != ixb);
        bool s1 = (ix1c != ixb);
        float w00 = wy0 * wx0, w01 = wy0 * wx1, w10 = wy1 * wx0, w11 = wy1 * wx1;
        float A  = (s0 ? 0.f : w00) + (s1 ? 0.f : w01);   // (y0, ixb)
        float Bw = (s0 ? w00 : 0.f) + (s1 ? w01 : 0.f);   // (y0, ixb+1)
        float Cw = (s0 ? 0.f : w10) + (s1 ? 0.f : w11);   // (y1, ixb)
        float Dw = (s0 ? w10 : 0.f) + (s1 ? w11 : 0.f);   // (y1, ixb+1)
        wts[tid] = make_float4(A, Bw, Cw, Dw);
        // position byte offsets in xtr: pos_idx * 64ch * 2B = idx<<7
        meta[tid] = make_int2(((iy0c << 7) + ixb) << 7, ((iy1c << 7) + ixb) << 7);
    }
    __syncthreads();

    {
        int p = tid >> 4;          // pixel
        int cq = tid & 15;         // channel quad
        const char* xb = (const char*)xtr + ((size_t)b << 21) + cq * 8;
#pragma unroll 3
        for (int k = 0; k < 9; ++k) {
            float4 wt4 = wts[p * 9 + k];
            int2 mm = meta[p * 9 + k];
            uint2 q00 = *(const uint2*)(xb + mm.x);          // (y0, ixb)   ch quad
            uint2 q01 = *(const uint2*)(xb + mm.x + 128);    // (y0, ixb+1)
            uint2 q10 = *(const uint2*)(xb + mm.y);          // (y1, ixb)
            uint2 q11 = *(const uint2*)(xb + mm.y + 128);    // (y1, ixb+1)
            float s0 = bflo(q00.x) * wt4.x + bflo(q01.x) * wt4.y
                     + bflo(q10.x) * wt4.z + bflo(q11.x) * wt4.w;
            float s1 = bfhi(q00.x) * wt4.x + bfhi(q01.x) * wt4.y
                     + bfhi(q10.x) * wt4.z + bfhi(q11.x) * wt4.w;
            float s2 = bflo(q00.y) * wt4.x + bflo(q01.y) * wt4.y
                     + bflo(q10.y) * wt4.z + bflo(q11.y) * wt4.w;
            float s3 = bfhi(q00.y) * wt4.x + bfhi(q01.y) * wt4.y
                     + bfhi(q10.y) * wt4.z + bfhi(q11.y) * wt4.w;
            *(uint2*)(&smp[p][k * 64 + cq * 4]) = make_uint2(
                (unsigned)f2bf(s0) | ((unsigned)f2bf(s1) << 16),
                (unsigned)f2bf(s2) | ((unsigned)f2bf(s3) << 16));
        }
    }
    __syncthreads();

    int wv = tid >> 6, lane = tid & 63;
    int r16 = lane & 15;          // A row (=o sub-index) and B col (=px)
    int g = lane >> 4;            // k-group
    floatx4 acc = {0.f, 0.f, 0.f, 0.f};
    const short8* ap = (const short8*)(wbf + (size_t)(wv * 16 + r16) * CK + g * 8);
    const unsigned short* bbase = &smp[r16][g * 8];
#pragma unroll
    for (int kk = 0; kk < 18; ++kk) {
        short8 a = ap[kk * 4];
        short8 bb = *(const short8*)(bbase + kk * 32);
        acc = __builtin_amdgcn_mfma_f32_16x16x32_bf16(a, bb, acc, 0, 0, 0);
    }

    size_t obase = ((size_t)(b * Cch + wv * 16 + g * 4)) << 14;
    int hw = (h << 7) + w0 + r16;
#pragma unroll
    for (int r = 0; r < 4; ++r)
        out[obase + ((size_t)r << 14) + hw] = acc[r];
}

// ---------------------------------------------------------------------------
extern "C" void kernel_launch(void* const* d_in, const int* in_sizes, int n_in,
                              void* d_out, int out_size, void* d_ws, size_t ws_size,
                              hipStream_t stream) {
    const float* x      = (const float*)d_in[0];
    const float* ref    = (const float*)d_in[1];
    const float* wo     = (const float*)d_in[2];
    const float* bias   = (const float*)d_in[3];
    const float* weight = (const float*)d_in[4];
    float* out = (float*)d_out;

    unsigned short* w9  = (unsigned short*)d_ws;                      // 72 KB
    unsigned short* wbf = (unsigned short*)((char*)d_ws + 131072);    // 72 KB
    float* offs         = (float*)((char*)d_ws + 262144);             // 4.5 MB
    unsigned short* xtr = (unsigned short*)((char*)d_ws + 4980736);   // 8.4 MB

    hipLaunchKernelGGL(convert_w, dim3((Cch * CK + 255) / 256), dim3(256), 0, stream,
                       weight, wbf);
    hipLaunchKernelGGL(convert_w9, dim3((9 * 32 * 128 + 255) / 256), dim3(256), 0, stream,
                       wo, w9);
    hipLaunchKernelGGL(transpose_x, dim3(Bsz * 256), dim3(256), 0, stream, x, xtr);
    hipLaunchKernelGGL(offset_mfma, dim3(Bsz * Hh * (Ww / 16)), dim3(256), 0, stream,
                       x, ref, w9, bias, offs);
    hipLaunchKernelGGL(deform_mfma, dim3(Bsz * Hh * (Ww / 16)), dim3(256), 0, stream,
                       xtr, wbf, offs, out);
}